// Round 1
// baseline (585.183 us; speedup 1.0000x reference)
//
#include <hip/hip_runtime.h>
#include <stdint.h>

#define NB 4
#define DK 128
#define DV 512
#define NQ 4096
#define NM 8192
#define SCALE 0.08838834764831845f   // 1/sqrt(128)

typedef unsigned short u16;
typedef __attribute__((ext_vector_type(8))) short short8;   // bf16x8 MFMA frag (4 VGPR)
typedef __attribute__((ext_vector_type(4))) float f32x4;    // fp32 accum frag

__device__ __forceinline__ u16 f2bf(float x){
  unsigned u = __float_as_uint(x);
  return (u16)((u + 0x7fffu + ((u >> 16) & 1u)) >> 16);     // RNE, inputs are finite
}

// in[b][D][N] f32  ->  out[b][N][D] bf16, scaled. 64x64 LDS tiles.
template<int D, int N>
__global__ void k_tconv(const float* __restrict__ in, u16* __restrict__ out, float scale){
  const int tilesN = N / 64;
  int id = blockIdx.x;
  int b  = id / ((D/64) * tilesN);
  int r  = id % ((D/64) * tilesN);
  int dt = r / tilesN, nt = r % tilesN;
  const float* inb = in + (size_t)b * D * N;
  u16* outb = out + (size_t)b * N * D;
  __shared__ float tile[64][65];
  int c  = threadIdx.x & 63;
  int r4 = threadIdx.x >> 6;
#pragma unroll
  for (int rr = 0; rr < 16; ++rr){
    int row = rr * 4 + r4;
    tile[row][c] = inb[(size_t)(dt*64 + row) * N + nt*64 + c] * scale;
  }
  __syncthreads();
#pragma unroll
  for (int rr = 0; rr < 16; ++rr){
    int n = rr * 4 + r4;
    outb[(size_t)(nt*64 + n) * D + dt*64 + c] = f2bf(tile[c][n]);
  }
}

// elementwise f32 -> bf16 (same layout), float4-vectorized
__global__ void k_conv(const float* __restrict__ in, u16* __restrict__ out, int n4){
  int i = blockIdx.x * blockDim.x + threadIdx.x;
  int stride = gridDim.x * blockDim.x;
  const float4* in4 = (const float4*)in;
  uint2* out2 = (uint2*)out;
  for (; i < n4; i += stride){
    float4 v = in4[i];
    uint2 o;
    o.x = ((unsigned)f2bf(v.y) << 16) | (unsigned)f2bf(v.x);
    o.y = ((unsigned)f2bf(v.w) << 16) | (unsigned)f2bf(v.z);
    out2[i] = o;
  }
}

// valid[b] = any(qm[b]) && any(mm[b])
__global__ void k_valid(const int* __restrict__ qm, const int* __restrict__ mm, int* __restrict__ valid){
  int b = blockIdx.x;
  int anyq = 0, anym = 0;
  for (int i = threadIdx.x; i < NQ; i += 256) anyq |= qm[b*NQ + i];
  for (int i = threadIdx.x; i < NM; i += 256) anym |= mm[b*NM + i];
  __shared__ int sh[256];
  sh[threadIdx.x] = ((anyq != 0) ? 1 : 0) | ((anym != 0) ? 2 : 0);
  __syncthreads();
  for (int s = 128; s > 0; s >>= 1){
    if (threadIdx.x < s) sh[threadIdx.x] |= sh[threadIdx.x + s];
    __syncthreads();
  }
  if (threadIdx.x == 0) valid[b] = ((sh[0] & 1) && (sh[0] & 2)) ? 1 : 0;
}

// Fused flash kernel.
// Grid: 256 WGs = b(4) x qblock(32, BQ=128) x dvhalf(2, 256 dv each). 512 threads (8 waves).
// Wave w: softmax strip q in [q0+16w, q0+16w+16); PV dv rows [dv0+32w, dv0+32w+32).
__global__ __launch_bounds__(512, 2) void k_attn(
    const u16* __restrict__ qkT,   // [B][NQ][DK] bf16, pre-scaled by 1/sqrt(DK)
    const u16* __restrict__ mkT,   // [B][NM][DK] bf16
    const u16* __restrict__ mvB,   // [B][DV][NM] bf16
    const float* __restrict__ qval,// [B][DV][NQ] f32
    const int* __restrict__ qmask, // [B][NQ]
    const int* __restrict__ mmask, // [B][NM]
    const int* __restrict__ validf,// [B]
    float* __restrict__ out)       // [B][DV][NQ] f32
{
  __shared__ u16 lds_k[64][136];     // K^T tile [m][d], 128+8 pad (row 272 B)
  __shared__ u16 lds_pT[128][72];    // P^T [q][m], 64+8 pad (row 144 B)
  __shared__ float lds_alpha[128];
  __shared__ float lds_mm[64];

  int tid = threadIdx.x;
  int b   = blockIdx.x >> 6;
  int rem = blockIdx.x & 63;
  int qb  = rem >> 1, dvh = rem & 1;
  int q0  = qb * 128, dv0 = dvh * 256;
  int w    = tid >> 6, lane = tid & 63;
  int g    = lane >> 4, lr   = lane & 15;

  const u16* qkTb = qkT + (size_t)b * NQ * DK;
  const u16* mkTb = mkT + (size_t)b * NM * DK;
  const u16* mvBb = mvB + (size_t)b * DV * NM;
  const int* mmb  = mmask + b * NM;

  // preload Q fragments for this wave's strip (B-operand: k(g,i) = 8g+i per 32-k step)
  int qs = q0 + w * 16;
  short8 qfrag[4];
#pragma unroll
  for (int ks = 0; ks < 4; ++ks)
    qfrag[ks] = *(const short8*)&qkTb[(size_t)(qs + lr) * DK + ks*32 + g*8];

  f32x4 acc[2][8];
#pragma unroll
  for (int i = 0; i < 2; ++i)
#pragma unroll
    for (int j = 0; j < 8; ++j)
      acc[i][j] = (f32x4){0.f, 0.f, 0.f, 0.f};
  float mrun = -1e30f, lrun = 0.f;

  for (int mt = 0; mt < NM/64; ++mt){
    int m0 = mt * 64;
    { // stage K^T tile: 64 rows x 128 bf16, 32 B per thread
      int row = tid >> 3, seg = tid & 7;
      const u16* src = mkTb + (size_t)(m0 + row) * DK + seg * 16;
      short8 v0 = *(const short8*)(src);
      short8 v1 = *(const short8*)(src + 8);
      *(short8*)&lds_k[row][seg*16]     = v0;
      *(short8*)&lds_k[row][seg*16 + 8] = v1;
    }
    if (tid < 64) lds_mm[tid] = (mmb[m0 + tid] != 0) ? 1.0f : 0.0f;
    __syncthreads();

    // ---- S strip: [64 m][16 q], A = K^T tile (LDS), B = Q frags (regs)
    f32x4 sfr[4];
#pragma unroll
    for (int mf = 0; mf < 4; ++mf){
      f32x4 c = (f32x4){0.f, 0.f, 0.f, 0.f};
#pragma unroll
      for (int ks = 0; ks < 4; ++ks){
        short8 a = *(const short8*)&lds_k[mf*16 + lr][ks*32 + g*8];
        c = __builtin_amdgcn_mfma_f32_16x16x32_bf16(a, qfrag[ks], c, 0, 0, 0);
      }
      sfr[mf] = c;
    }

    // ---- online softmax (columns q; lane group {lr,lr+16,lr+32,lr+48} shares q)
    float tmax = -1e30f;
#pragma unroll
    for (int mf = 0; mf < 4; ++mf)
#pragma unroll
      for (int r = 0; r < 4; ++r) tmax = fmaxf(tmax, sfr[mf][r]);
    tmax = fmaxf(tmax, __shfl_xor(tmax, 16, 64));
    tmax = fmaxf(tmax, __shfl_xor(tmax, 32, 64));
    float mnew  = fmaxf(mrun, tmax);
    float alpha = __expf(mrun - mnew);
    float tsum  = 0.f;
#pragma unroll
    for (int mf = 0; mf < 4; ++mf){
      f32x4 mmf = *(const f32x4*)&lds_mm[mf*16 + g*4];
#pragma unroll
      for (int r = 0; r < 4; ++r){
        float p = mmf[r] * __expf(sfr[mf][r] - mnew);  // masked -> exactly 0
        sfr[mf][r] = p;
        tsum += p;
      }
    }
    tsum += __shfl_xor(tsum, 16, 64);
    tsum += __shfl_xor(tsum, 32, 64);
    lrun = lrun * alpha + tsum;
    mrun = mnew;
    if (g == 0) lds_alpha[w*16 + lr] = alpha;
    // write P^T bf16 (lane owns q = qs+lr, m = mf*16 + 4g + r)
#pragma unroll
    for (int mf = 0; mf < 4; ++mf){
      uint2 pk;
      pk.x = ((unsigned)f2bf(sfr[mf][1]) << 16) | (unsigned)f2bf(sfr[mf][0]);
      pk.y = ((unsigned)f2bf(sfr[mf][3]) << 16) | (unsigned)f2bf(sfr[mf][2]);
      *(uint2*)&lds_pT[w*16 + lr][mf*16 + g*4] = pk;
    }
    __syncthreads();

    // ---- PV: acc[dv][q] = acc*alpha + V_tile · P  (A = V from global, B = P^T from LDS)
    short8 vf[2][2];
#pragma unroll
    for (int df = 0; df < 2; ++df)
#pragma unroll
      for (int ks2 = 0; ks2 < 2; ++ks2)
        vf[df][ks2] = *(const short8*)&mvBb[(size_t)(dv0 + w*32 + df*16 + lr) * NM
                                            + m0 + ks2*32 + g*8];
#pragma unroll
    for (int qf = 0; qf < 8; ++qf){
      float a_ = lds_alpha[qf*16 + lr];
#pragma unroll
      for (int df = 0; df < 2; ++df)
#pragma unroll
        for (int r = 0; r < 4; ++r) acc[df][qf][r] *= a_;
#pragma unroll
      for (int ks2 = 0; ks2 < 2; ++ks2){
        short8 pf = *(const short8*)&lds_pT[qf*16 + lr][ks2*32 + g*8];
#pragma unroll
        for (int df = 0; df < 2; ++df)
          acc[df][qf] = __builtin_amdgcn_mfma_f32_16x16x32_bf16(vf[df][ks2], pf, acc[df][qf], 0, 0, 0);
      }
    }
    __syncthreads();
  }

  // ---- epilogue: out = qval + gate * acc / l
  if (g == 0) lds_alpha[w*16 + lr] = lrun;
  __syncthreads();
  int vb = validf[b];
  const int* qmb = qmask + b * NQ;
  const float* qvb = qval + (size_t)b * DV * NQ;
  float* outb = out + (size_t)b * DV * NQ;
#pragma unroll
  for (int qf = 0; qf < 8; ++qf){
    int q = q0 + qf*16 + lr;
    float l_ = lds_alpha[qf*16 + lr];
    float rl = (l_ > 0.f) ? 1.0f / l_ : 0.f;
    float gate = (vb && qmb[q]) ? rl : 0.f;
#pragma unroll
    for (int df = 0; df < 2; ++df){
#pragma unroll
      for (int r = 0; r < 4; ++r){
        int dv = dv0 + w*32 + df*16 + g*4 + r;
        size_t idx = (size_t)dv * NQ + q;
        outb[idx] = qvb[idx] + acc[df][qf][r] * gate;
      }
    }
  }
}

extern "C" void kernel_launch(void* const* d_in, const int* in_sizes, int n_in,
                              void* d_out, int out_size, void* d_ws, size_t ws_size,
                              hipStream_t stream) {
  const float* qkey  = (const float*)d_in[0];
  const float* qval  = (const float*)d_in[1];
  const int*   qmask = (const int*)d_in[2];
  const float* mkey  = (const float*)d_in[3];
  const float* mval  = (const float*)d_in[4];
  const int*   mmask = (const int*)d_in[5];
  float* out = (float*)d_out;

  char* ws = (char*)d_ws;
  // ws layout (bytes): qkT 4 MiB | mkT 8 MiB | mvB 32 MiB | valid flags
  u16* qkT = (u16*)(ws);
  u16* mkT = (u16*)(ws + (size_t)4*1024*1024);
  u16* mvB = (u16*)(ws + (size_t)12*1024*1024);
  int* validf = (int*)(ws + (size_t)12*1024*1024 + (size_t)NB*DV*NM*2);

  k_tconv<DK, NQ><<<dim3(NB * (DK/64) * (NQ/64)), dim3(256), 0, stream>>>(qkey, qkT, SCALE);
  k_tconv<DK, NM><<<dim3(NB * (DK/64) * (NM/64)), dim3(256), 0, stream>>>(mkey, mkT, 1.0f);
  k_conv<<<dim3(4096), dim3(256), 0, stream>>>(mval, mvB, NB*DV*NM/4);
  k_valid<<<dim3(NB), dim3(256), 0, stream>>>(qmask, mmask, validf);
  k_attn<<<dim3(256), dim3(512), 0, stream>>>(qkT, mkT, mvB, qval, qmask, mmask, validf, out);
}